// Round 10
// baseline (691.799 us; speedup 1.0000x reference)
//
#include <hip/hip_runtime.h>
#include <hip/hip_bf16.h>

// E71 Delta cell: T=2048, B=16, D=1024, N=128
// proj layout in ws: [t][b][512] f32, cols 0..127=k_hat (after norm pass),
// 128..255=v, 256..383=q, 384..511=bx

#define T_STEPS 2048
#define NB 16
#define ND 128
#define KD 1024
#define PSTRIDE 512

typedef __attribute__((ext_vector_type(4))) float f32x4;
typedef __attribute__((ext_vector_type(2))) float f32x2;
typedef __attribute__((ext_vector_type(8))) short short8v;

__device__ __forceinline__ unsigned short f2bf(float f) {
  union { float f; unsigned int u; } c; c.f = f;
  unsigned int u = c.u;
  unsigned int r = u + 0x7fffu + ((u >> 16) & 1u);   // round-to-nearest-even
  return (unsigned short)(r >> 16);
}

// ---------------------------------------------------------------------------
// Projection GEMM (unchanged, ~56us): bf16 MFMA, 128x128 tile, BK=64,
// XOR-swizzled LDS.
// ---------------------------------------------------------------------------
__global__ __launch_bounds__(256) void proj_gemm(
    const float* __restrict__ X,
    const float* __restrict__ Wk, const float* __restrict__ Wv,
    const float* __restrict__ Wq, const float* __restrict__ Wb,
    float* __restrict__ C)
{
  __shared__ unsigned short As[128 * 64];
  __shared__ unsigned short Bs[128 * 64];
  const int tid = threadIdx.x;
  const int bm = blockIdx.x;
  const int bn = blockIdx.y;
  const float* W = (bn == 0) ? Wk : ((bn == 1) ? Wv : ((bn == 2) ? Wq : Wb));
  const int lane = tid & 63;
  const int wave = tid >> 6;
  const int wr = wave >> 1, wc = wave & 1;

  f32x4 acc[4][4];
#pragma unroll
  for (int i = 0; i < 4; i++)
#pragma unroll
    for (int j = 0; j < 4; j++) acc[i][j] = (f32x4){0.f, 0.f, 0.f, 0.f};

  for (int k0 = 0; k0 < KD; k0 += 64) {
    __syncthreads();
#pragma unroll
    for (int c = 0; c < 4; c++) {
      const int g = tid + c * 256;
      const int row = g >> 3;
      const int ch = g & 7;
      const int pos = ((ch ^ (row & 7)) * 8);
      {
        const float* ga = X + (size_t)(bm * 128 + row) * KD + k0 + ch * 8;
        float4 f0 = *(const float4*)(ga);
        float4 f1 = *(const float4*)(ga + 4);
        union { unsigned short u[8]; short8v v; } pk2;
        pk2.u[0] = f2bf(f0.x); pk2.u[1] = f2bf(f0.y);
        pk2.u[2] = f2bf(f0.z); pk2.u[3] = f2bf(f0.w);
        pk2.u[4] = f2bf(f1.x); pk2.u[5] = f2bf(f1.y);
        pk2.u[6] = f2bf(f1.z); pk2.u[7] = f2bf(f1.w);
        *reinterpret_cast<short8v*>(&As[row * 64 + pos]) = pk2.v;
      }
      {
        const float* gb = W + (size_t)row * KD + k0 + ch * 8;
        float4 f0 = *(const float4*)(gb);
        float4 f1 = *(const float4*)(gb + 4);
        union { unsigned short u[8]; short8v v; } pk2;
        pk2.u[0] = f2bf(f0.x); pk2.u[1] = f2bf(f0.y);
        pk2.u[2] = f2bf(f0.z); pk2.u[3] = f2bf(f0.w);
        pk2.u[4] = f2bf(f1.x); pk2.u[5] = f2bf(f1.y);
        pk2.u[6] = f2bf(f1.z); pk2.u[7] = f2bf(f1.w);
        *reinterpret_cast<short8v*>(&Bs[row * 64 + pos]) = pk2.v;
      }
    }
    __syncthreads();
#pragma unroll
    for (int kk = 0; kk < 2; kk++) {
      const int ch = kk * 4 + (lane >> 4);
      short8v a[4], b[4];
#pragma unroll
      for (int i = 0; i < 4; i++) {
        const int ar = wr * 64 + i * 16 + (lane & 15);
        a[i] = *reinterpret_cast<const short8v*>(&As[ar * 64 + ((ch ^ (ar & 7)) * 8)]);
        const int br = wc * 64 + i * 16 + (lane & 15);
        b[i] = *reinterpret_cast<const short8v*>(&Bs[br * 64 + ((ch ^ (br & 7)) * 8)]);
      }
#pragma unroll
      for (int i = 0; i < 4; i++)
#pragma unroll
        for (int j = 0; j < 4; j++)
          acc[i][j] = __builtin_amdgcn_mfma_f32_16x16x32_bf16(a[i], b[j], acc[i][j], 0, 0, 0);
    }
  }
#pragma unroll
  for (int i = 0; i < 4; i++)
#pragma unroll
    for (int j = 0; j < 4; j++)
#pragma unroll
      for (int r = 0; r < 4; r++) {
        const int row = bm * 128 + wr * 64 + i * 16 + (lane >> 4) * 4 + r;
        const int col = bn * 128 + wc * 64 + j * 16 + (lane & 15);
        C[(size_t)row * PSTRIDE + col] = acc[i][j][r];
      }
}

// ---------------------------------------------------------------------------
// k-normalization pre-pass: proj[row][0:128] <- k / (||k|| + eps).
// ---------------------------------------------------------------------------
__global__ __launch_bounds__(256) void norm_k(float* __restrict__ proj) {
  const int lane = threadIdx.x & 63;
  const int wid = (blockIdx.x * 256 + threadIdx.x) >> 6;
  float* rowp = proj + (size_t)wid * PSTRIDE;
  float2 kv = *reinterpret_cast<float2*>(rowp + lane * 2);
  float ss = kv.x * kv.x + kv.y * kv.y;
  ss += __shfl_xor(ss, 1);
  ss += __shfl_xor(ss, 2);
  ss += __shfl_xor(ss, 4);
  ss += __shfl_xor(ss, 8);
  ss += __shfl_xor(ss, 16);
  ss += __shfl_xor(ss, 32);
  const float rn = 1.0f / (sqrtf(ss) + 1e-6f);
  kv.x *= rn; kv.y *= rn;
  *reinterpret_cast<float2*>(rowp + lane * 2) = kv;
}

// ---------------------------------------------------------------------------
// Sequential scan, R10: ONE ROW PER WAVE.
// 2048 single-wave blocks (16 batches x 128 rows) -> 8 waves/CU = 2 chains
// per SIMD (TLP hides chain+memory stalls). batch = bid&15 so a CU's 8
// waves share the same batch -> same k/q rows each step -> L1 dedupe.
// Per lane: S slice f32x2 (cols lane*2); per-buf loads = 4 insts only
// (k,q dwordx2 per lane; v,bx lane-uniform dwords) - no 4x redundancy.
// Chain-decoupled r (R9 identity): r = pre0 + crp*kkp; od = reduce(S'.q)
// directly (terminal, off-chain). Reduce = 4 DPP row_ror + shfl_xor 16/32.
// Depth-8 asm ring, uniform counted vmcnt(24) (4 loads+1 store per slot
// drains exactly one buf; CUR loaded 8 slots ago, NXT 7 -> always resident).
// ---------------------------------------------------------------------------
__device__ __forceinline__ float sum64(float v) {
  v += __int_as_float(__builtin_amdgcn_update_dpp(0, __float_as_int(v), 0x121, 0xF, 0xF, true)); // row_ror:1
  v += __int_as_float(__builtin_amdgcn_update_dpp(0, __float_as_int(v), 0x122, 0xF, 0xF, true)); // row_ror:2
  v += __int_as_float(__builtin_amdgcn_update_dpp(0, __float_as_int(v), 0x124, 0xF, 0xF, true)); // row_ror:4
  v += __int_as_float(__builtin_amdgcn_update_dpp(0, __float_as_int(v), 0x128, 0xF, 0xF, true)); // row_ror:8
  v += __shfl_xor(v, 16);
  v += __shfl_xor(v, 32);
  return v;
}

struct Buf { f32x2 kn, q; float v, bx; };

// pk = row base + lane*2 floats (k at +0, q at +1024B);
// pv = row base + 128 + row (v at +0, bx at +1024B); lane-uniform.
__device__ __forceinline__ void load_buf_asm(const float* pk, const float* pv, Buf& b) {
  asm volatile("global_load_dwordx2 %0, %1, off"             : "=v"(b.kn) : "v"(pk));
  asm volatile("global_load_dwordx2 %0, %1, off offset:1024" : "=v"(b.q)  : "v"(pk));
  asm volatile("global_load_dword %0, %1, off"               : "=v"(b.v)  : "v"(pv));
  asm volatile("global_load_dword %0, %1, off offset:1024"   : "=v"(b.bx) : "v"(pv));
}

__device__ __forceinline__ float fin(float od) {
  return od * od * __builtin_amdgcn_rcpf(1.0f + __expf(-od));
}

__global__ __launch_bounds__(64) void scan_kernel(
    const float* __restrict__ proj, const float* __restrict__ S_in,
    const float* __restrict__ d_beta, const float* __restrict__ b_beta,
    float* __restrict__ out, float* __restrict__ S_out)
{
  const int lane = threadIdx.x & 63;
  const int batch = blockIdx.x & 15;   // CU's co-resident blocks share batch
  const int row = blockIdx.x >> 4;     // 0..127
  const bool w0 = (lane == 0);

  f32x2 S2 = *reinterpret_cast<const f32x2*>(
      S_in + ((size_t)batch * ND + row) * ND + lane * 2);
  const float db = d_beta[row];
  const float bb = b_beta[row];

  const float* pb = proj + (size_t)batch * PSTRIDE;
  const float* pkb = pb + lane * 2;     // k; q at +1024B
  const float* pvb = pb + 128 + row;    // v; bx at +1024B (uniform)
  const size_t sstep = (size_t)NB * PSTRIDE;
  float* outp = out + (size_t)batch * ND + row;
  const size_t ostep = (size_t)NB * ND;

  Buf B0, B1, B2, B3, B4, B5, B6, B7;
  load_buf_asm(pkb + 0 * sstep, pvb + 0 * sstep, B0);
  load_buf_asm(pkb + 1 * sstep, pvb + 1 * sstep, B1);
  load_buf_asm(pkb + 2 * sstep, pvb + 2 * sstep, B2);
  load_buf_asm(pkb + 3 * sstep, pvb + 3 * sstep, B3);
  load_buf_asm(pkb + 4 * sstep, pvb + 4 * sstep, B4);
  load_buf_asm(pkb + 5 * sstep, pvb + 5 * sstep, B5);
  load_buf_asm(pkb + 6 * sstep, pvb + 6 * sstep, B6);
  load_buf_asm(pkb + 7 * sstep, pvb + 7 * sstep, B7);

#define WAIT24 do { asm volatile("s_waitcnt vmcnt(24)" ::: "memory"); \
                    __builtin_amdgcn_sched_barrier(0); } while (0)

  // prologue: B0,B1 ready (32 outstanding -> 24 drains exactly B0,B1)
  WAIT24;
  float pre0;
  {
    const f32x2 p = S2 * B0.kn;
    pre0 = sum64(p.x + p.y);            // r_0 = S0.k0, no correction
  }
  float kkp = 0.f, crp = 0.f;

#define SLOT(CUR, NXT, tnext)                                             \
  do {                                                                    \
    WAIT24;                                                               \
    /* off-chain dots+reduces (CUR, NXT resident) */                      \
    const f32x2 dp = S2 * NXT.kn;                                         \
    const f32x2 dk = CUR.kn * NXT.kn;                                     \
    const float pre1 = sum64(dp.x + dp.y);                                \
    const float kk1  = sum64(dk.x + dk.y);                                \
    /* serial chain */                                                    \
    const float r  = fmaf(crp, kkp, pre0);                                \
    const float lg = fmaf(db, r, CUR.bx + bb);                            \
    const float beta = __builtin_amdgcn_rcpf(1.0f + __expf(-lg));         \
    const float cr = beta * (CUR.v - r);                                  \
    /* S update + terminal output */                                      \
    const f32x2 cr2 = {cr, cr};                                           \
    S2 = __builtin_elementwise_fma(cr2, CUR.kn, S2);                      \
    const f32x2 ov = S2 * CUR.q;                                          \
    const float od = sum64(ov.x + ov.y);                                  \
    if (w0) *outp = fin(od);                                              \
    outp += ostep;                                                        \
    pre0 = pre1; kkp = kk1; crp = cr;                                     \
    load_buf_asm(pkb + (size_t)(tnext) * sstep,                           \
                 pvb + (size_t)(tnext) * sstep, CUR);                     \
  } while (0)

  for (int t = 0; t < T_STEPS; t += 8) {
    const int t0 = (t +  8 < T_STEPS) ? t +  8 : T_STEPS - 1;
    const int t1 = (t +  9 < T_STEPS) ? t +  9 : T_STEPS - 1;
    const int t2 = (t + 10 < T_STEPS) ? t + 10 : T_STEPS - 1;
    const int t3 = (t + 11 < T_STEPS) ? t + 11 : T_STEPS - 1;
    const int t4 = (t + 12 < T_STEPS) ? t + 12 : T_STEPS - 1;
    const int t5 = (t + 13 < T_STEPS) ? t + 13 : T_STEPS - 1;
    const int t6 = (t + 14 < T_STEPS) ? t + 14 : T_STEPS - 1;
    const int t7 = (t + 15 < T_STEPS) ? t + 15 : T_STEPS - 1;
    SLOT(B0, B1, t0);
    SLOT(B1, B2, t1);
    SLOT(B2, B3, t2);
    SLOT(B3, B4, t3);
    SLOT(B4, B5, t4);
    SLOT(B5, B6, t5);
    SLOT(B6, B7, t6);
    SLOT(B7, B0, t7);
  }
#undef SLOT
#undef WAIT24

  asm volatile("s_waitcnt vmcnt(0)" ::: "memory");
  *reinterpret_cast<f32x2*>(
      S_out + ((size_t)batch * ND + row) * ND + lane * 2) = S2;
}

extern "C" void kernel_launch(void* const* d_in, const int* in_sizes, int n_in,
                              void* d_out, int out_size, void* d_ws, size_t ws_size,
                              hipStream_t stream) {
  const float* x  = (const float*)d_in[0];   // [2048][16][1024]
  const float* S0 = (const float*)d_in[1];   // [16][128][128]
  const float* Wk = (const float*)d_in[2];
  const float* Wv = (const float*)d_in[3];
  const float* Wq = (const float*)d_in[4];
  const float* Wb = (const float*)d_in[5];
  const float* db = (const float*)d_in[6];
  const float* bb = (const float*)d_in[7];
  float* out  = (float*)d_out;                           // [2048][16][128]
  float* Sout = out + (size_t)T_STEPS * NB * ND;         // [16][128][128]
  float* proj = (float*)d_ws;                            // [32768][512] = 64 MB

  dim3 ggrid(256, 4);
  proj_gemm<<<ggrid, 256, 0, stream>>>(x, Wk, Wv, Wq, Wb, proj);
  norm_k<<<8192, 256, 0, stream>>>(proj);
  scan_kernel<<<2048, 64, 0, stream>>>(proj, S0, db, bb, out, Sout);
}

// Round 11
// 690.936 us; speedup vs baseline: 1.0012x; 1.0012x over previous
//
#include <hip/hip_runtime.h>
#include <hip/hip_bf16.h>

// E71 Delta cell: T=2048, B=16, D=1024, N=128
// proj layout in ws: [t][b][512] f32, cols 0..127=k_hat (after norm pass),
// 128..255=v, 256..383=q, 384..511=bx

#define T_STEPS 2048
#define NB 16
#define ND 128
#define KD 1024
#define PSTRIDE 512

typedef __attribute__((ext_vector_type(4))) float f32x4;
typedef __attribute__((ext_vector_type(2))) float f32x2;
typedef __attribute__((ext_vector_type(8))) short short8v;

__device__ __forceinline__ unsigned short f2bf(float f) {
  union { float f; unsigned int u; } c; c.f = f;
  unsigned int u = c.u;
  unsigned int r = u + 0x7fffu + ((u >> 16) & 1u);   // round-to-nearest-even
  return (unsigned short)(r >> 16);
}

// ---------------------------------------------------------------------------
// Projection GEMM (unchanged, ~56us): bf16 MFMA, 128x128 tile, BK=64,
// XOR-swizzled LDS.
// ---------------------------------------------------------------------------
__global__ __launch_bounds__(256) void proj_gemm(
    const float* __restrict__ X,
    const float* __restrict__ Wk, const float* __restrict__ Wv,
    const float* __restrict__ Wq, const float* __restrict__ Wb,
    float* __restrict__ C)
{
  __shared__ unsigned short As[128 * 64];
  __shared__ unsigned short Bs[128 * 64];
  const int tid = threadIdx.x;
  const int bm = blockIdx.x;
  const int bn = blockIdx.y;
  const float* W = (bn == 0) ? Wk : ((bn == 1) ? Wv : ((bn == 2) ? Wq : Wb));
  const int lane = tid & 63;
  const int wave = tid >> 6;
  const int wr = wave >> 1, wc = wave & 1;

  f32x4 acc[4][4];
#pragma unroll
  for (int i = 0; i < 4; i++)
#pragma unroll
    for (int j = 0; j < 4; j++) acc[i][j] = (f32x4){0.f, 0.f, 0.f, 0.f};

  for (int k0 = 0; k0 < KD; k0 += 64) {
    __syncthreads();
#pragma unroll
    for (int c = 0; c < 4; c++) {
      const int g = tid + c * 256;
      const int row = g >> 3;
      const int ch = g & 7;
      const int pos = ((ch ^ (row & 7)) * 8);
      {
        const float* ga = X + (size_t)(bm * 128 + row) * KD + k0 + ch * 8;
        float4 f0 = *(const float4*)(ga);
        float4 f1 = *(const float4*)(ga + 4);
        union { unsigned short u[8]; short8v v; } pk2;
        pk2.u[0] = f2bf(f0.x); pk2.u[1] = f2bf(f0.y);
        pk2.u[2] = f2bf(f0.z); pk2.u[3] = f2bf(f0.w);
        pk2.u[4] = f2bf(f1.x); pk2.u[5] = f2bf(f1.y);
        pk2.u[6] = f2bf(f1.z); pk2.u[7] = f2bf(f1.w);
        *reinterpret_cast<short8v*>(&As[row * 64 + pos]) = pk2.v;
      }
      {
        const float* gb = W + (size_t)row * KD + k0 + ch * 8;
        float4 f0 = *(const float4*)(gb);
        float4 f1 = *(const float4*)(gb + 4);
        union { unsigned short u[8]; short8v v; } pk2;
        pk2.u[0] = f2bf(f0.x); pk2.u[1] = f2bf(f0.y);
        pk2.u[2] = f2bf(f0.z); pk2.u[3] = f2bf(f0.w);
        pk2.u[4] = f2bf(f1.x); pk2.u[5] = f2bf(f1.y);
        pk2.u[6] = f2bf(f1.z); pk2.u[7] = f2bf(f1.w);
        *reinterpret_cast<short8v*>(&Bs[row * 64 + pos]) = pk2.v;
      }
    }
    __syncthreads();
#pragma unroll
    for (int kk = 0; kk < 2; kk++) {
      const int ch = kk * 4 + (lane >> 4);
      short8v a[4], b[4];
#pragma unroll
      for (int i = 0; i < 4; i++) {
        const int ar = wr * 64 + i * 16 + (lane & 15);
        a[i] = *reinterpret_cast<const short8v*>(&As[ar * 64 + ((ch ^ (ar & 7)) * 8)]);
        const int br = wc * 64 + i * 16 + (lane & 15);
        b[i] = *reinterpret_cast<const short8v*>(&Bs[br * 64 + ((ch ^ (br & 7)) * 8)]);
      }
#pragma unroll
      for (int i = 0; i < 4; i++)
#pragma unroll
        for (int j = 0; j < 4; j++)
          acc[i][j] = __builtin_amdgcn_mfma_f32_16x16x32_bf16(a[i], b[j], acc[i][j], 0, 0, 0);
    }
  }
#pragma unroll
  for (int i = 0; i < 4; i++)
#pragma unroll
    for (int j = 0; j < 4; j++)
#pragma unroll
      for (int r = 0; r < 4; r++) {
        const int row = bm * 128 + wr * 64 + i * 16 + (lane >> 4) * 4 + r;
        const int col = bn * 128 + wc * 64 + j * 16 + (lane & 15);
        C[(size_t)row * PSTRIDE + col] = acc[i][j][r];
      }
}

// ---------------------------------------------------------------------------
// k-normalization pre-pass: proj[row][0:128] <- k / (||k|| + eps).
// ---------------------------------------------------------------------------
__global__ __launch_bounds__(256) void norm_k(float* __restrict__ proj) {
  const int lane = threadIdx.x & 63;
  const int wid = (blockIdx.x * 256 + threadIdx.x) >> 6;
  float* rowp = proj + (size_t)wid * PSTRIDE;
  float2 kv = *reinterpret_cast<float2*>(rowp + lane * 2);
  float ss = kv.x * kv.x + kv.y * kv.y;
  ss += __shfl_xor(ss, 1);
  ss += __shfl_xor(ss, 2);
  ss += __shfl_xor(ss, 4);
  ss += __shfl_xor(ss, 8);
  ss += __shfl_xor(ss, 16);
  ss += __shfl_xor(ss, 32);
  const float rn = 1.0f / (sqrtf(ss) + 1e-6f);
  kv.x *= rn; kv.y *= rn;
  *reinterpret_cast<float2*>(rowp + lane * 2) = kv;
}

// ---------------------------------------------------------------------------
// Sequential scan, R11 = R10 (one row per wave) + __launch_bounds__(64, 2).
// R10's geometry was right (Occ 18%, 2 chains/SIMD, no intra-wave load
// redundancy, co-resident waves share batch -> L1 dedupe of identical k/q
// addresses) but launch_bounds(64) let the compiler crush VGPR to 32 and
// spill the asm ring to scratch (WRITE_SIZE +5GB). min-waves=2 -> cap 256.
// 2048 single-wave blocks (batch = bid&15 invariant under the stride-256
// co-residency pattern; XCD = bid&7 = batch%8 -> L2 locality).
// Per lane: S slice f32x2 (cols lane*2); per-buf 4 loads (k,q dwordx2;
// v,bx wave-uniform dwords). Chain-decoupled r (R9 identity). Reduce =
// 4 DPP row_ror + shfl_xor 16/32. Depth-8 asm ring, counted vmcnt(24).
// ---------------------------------------------------------------------------
__device__ __forceinline__ float sum64(float v) {
  v += __int_as_float(__builtin_amdgcn_update_dpp(0, __float_as_int(v), 0x121, 0xF, 0xF, true)); // row_ror:1
  v += __int_as_float(__builtin_amdgcn_update_dpp(0, __float_as_int(v), 0x122, 0xF, 0xF, true)); // row_ror:2
  v += __int_as_float(__builtin_amdgcn_update_dpp(0, __float_as_int(v), 0x124, 0xF, 0xF, true)); // row_ror:4
  v += __int_as_float(__builtin_amdgcn_update_dpp(0, __float_as_int(v), 0x128, 0xF, 0xF, true)); // row_ror:8
  v += __shfl_xor(v, 16);
  v += __shfl_xor(v, 32);
  return v;
}

struct Buf { f32x2 kn, q; float v, bx; };

// pk = row base + lane*2 floats (k at +0, q at +1024B);
// pv = row base + 128 + row (v at +0, bx at +1024B); wave-uniform.
__device__ __forceinline__ void load_buf_asm(const float* pk, const float* pv, Buf& b) {
  asm volatile("global_load_dwordx2 %0, %1, off"             : "=v"(b.kn) : "v"(pk));
  asm volatile("global_load_dwordx2 %0, %1, off offset:1024" : "=v"(b.q)  : "v"(pk));
  asm volatile("global_load_dword %0, %1, off"               : "=v"(b.v)  : "v"(pv));
  asm volatile("global_load_dword %0, %1, off offset:1024"   : "=v"(b.bx) : "v"(pv));
}

__device__ __forceinline__ float fin(float od) {
  return od * od * __builtin_amdgcn_rcpf(1.0f + __expf(-od));
}

__global__ __launch_bounds__(64, 2) void scan_kernel(
    const float* __restrict__ proj, const float* __restrict__ S_in,
    const float* __restrict__ d_beta, const float* __restrict__ b_beta,
    float* __restrict__ out, float* __restrict__ S_out)
{
  const int lane = threadIdx.x & 63;
  const int batch = blockIdx.x & 15;   // CU's co-resident blocks share batch
  const int row = blockIdx.x >> 4;     // 0..127
  const bool w0 = (lane == 0);

  f32x2 S2 = *reinterpret_cast<const f32x2*>(
      S_in + ((size_t)batch * ND + row) * ND + lane * 2);
  const float db = d_beta[row];
  const float bb = b_beta[row];

  const float* pb = proj + (size_t)batch * PSTRIDE;
  const float* pkb = pb + lane * 2;     // k; q at +1024B
  const float* pvb = pb + 128 + row;    // v; bx at +1024B (uniform)
  const size_t sstep = (size_t)NB * PSTRIDE;
  float* outp = out + (size_t)batch * ND + row;
  const size_t ostep = (size_t)NB * ND;

  Buf B0, B1, B2, B3, B4, B5, B6, B7;
  load_buf_asm(pkb + 0 * sstep, pvb + 0 * sstep, B0);
  load_buf_asm(pkb + 1 * sstep, pvb + 1 * sstep, B1);
  load_buf_asm(pkb + 2 * sstep, pvb + 2 * sstep, B2);
  load_buf_asm(pkb + 3 * sstep, pvb + 3 * sstep, B3);
  load_buf_asm(pkb + 4 * sstep, pvb + 4 * sstep, B4);
  load_buf_asm(pkb + 5 * sstep, pvb + 5 * sstep, B5);
  load_buf_asm(pkb + 6 * sstep, pvb + 6 * sstep, B6);
  load_buf_asm(pkb + 7 * sstep, pvb + 7 * sstep, B7);

#define WAIT24 do { asm volatile("s_waitcnt vmcnt(24)" ::: "memory"); \
                    __builtin_amdgcn_sched_barrier(0); } while (0)

  // prologue: B0,B1 ready (32 outstanding -> 24 drains exactly B0,B1)
  WAIT24;
  float pre0;
  {
    const f32x2 p = S2 * B0.kn;
    pre0 = sum64(p.x + p.y);            // r_0 = S0.k0, no correction
  }
  float kkp = 0.f, crp = 0.f;

#define SLOT(CUR, NXT, tnext)                                             \
  do {                                                                    \
    WAIT24;                                                               \
    /* off-chain dots+reduces (CUR, NXT resident) */                      \
    const f32x2 dp = S2 * NXT.kn;                                         \
    const f32x2 dk = CUR.kn * NXT.kn;                                     \
    const float pre1 = sum64(dp.x + dp.y);                                \
    const float kk1  = sum64(dk.x + dk.y);                                \
    /* serial chain */                                                    \
    const float r  = fmaf(crp, kkp, pre0);                                \
    const float lg = fmaf(db, r, CUR.bx + bb);                            \
    const float beta = __builtin_amdgcn_rcpf(1.0f + __expf(-lg));         \
    const float cr = beta * (CUR.v - r);                                  \
    /* S update + terminal output */                                      \
    const f32x2 cr2 = {cr, cr};                                           \
    S2 = __builtin_elementwise_fma(cr2, CUR.kn, S2);                      \
    const f32x2 ov = S2 * CUR.q;                                          \
    const float od = sum64(ov.x + ov.y);                                  \
    if (w0) *outp = fin(od);                                              \
    outp += ostep;                                                        \
    pre0 = pre1; kkp = kk1; crp = cr;                                     \
    load_buf_asm(pkb + (size_t)(tnext) * sstep,                           \
                 pvb + (size_t)(tnext) * sstep, CUR);                     \
  } while (0)

  for (int t = 0; t < T_STEPS; t += 8) {
    const int t0 = (t +  8 < T_STEPS) ? t +  8 : T_STEPS - 1;
    const int t1 = (t +  9 < T_STEPS) ? t +  9 : T_STEPS - 1;
    const int t2 = (t + 10 < T_STEPS) ? t + 10 : T_STEPS - 1;
    const int t3 = (t + 11 < T_STEPS) ? t + 11 : T_STEPS - 1;
    const int t4 = (t + 12 < T_STEPS) ? t + 12 : T_STEPS - 1;
    const int t5 = (t + 13 < T_STEPS) ? t + 13 : T_STEPS - 1;
    const int t6 = (t + 14 < T_STEPS) ? t + 14 : T_STEPS - 1;
    const int t7 = (t + 15 < T_STEPS) ? t + 15 : T_STEPS - 1;
    SLOT(B0, B1, t0);
    SLOT(B1, B2, t1);
    SLOT(B2, B3, t2);
    SLOT(B3, B4, t3);
    SLOT(B4, B5, t4);
    SLOT(B5, B6, t5);
    SLOT(B6, B7, t6);
    SLOT(B7, B0, t7);
  }
#undef SLOT
#undef WAIT24

  asm volatile("s_waitcnt vmcnt(0)" ::: "memory");
  *reinterpret_cast<f32x2*>(
      S_out + ((size_t)batch * ND + row) * ND + lane * 2) = S2;
}

extern "C" void kernel_launch(void* const* d_in, const int* in_sizes, int n_in,
                              void* d_out, int out_size, void* d_ws, size_t ws_size,
                              hipStream_t stream) {
  const float* x  = (const float*)d_in[0];   // [2048][16][1024]
  const float* S0 = (const float*)d_in[1];   // [16][128][128]
  const float* Wk = (const float*)d_in[2];
  const float* Wv = (const float*)d_in[3];
  const float* Wq = (const float*)d_in[4];
  const float* Wb = (const float*)d_in[5];
  const float* db = (const float*)d_in[6];
  const float* bb = (const float*)d_in[7];
  float* out  = (float*)d_out;                           // [2048][16][128]
  float* Sout = out + (size_t)T_STEPS * NB * ND;         // [16][128][128]
  float* proj = (float*)d_ws;                            // [32768][512] = 64 MB

  dim3 ggrid(256, 4);
  proj_gemm<<<ggrid, 256, 0, stream>>>(x, Wk, Wv, Wq, Wb, proj);
  norm_k<<<8192, 256, 0, stream>>>(proj);
  scan_kernel<<<2048, 64, 0, stream>>>(proj, S0, db, bb, out, Sout);
}

// Round 12
// 576.850 us; speedup vs baseline: 1.1993x; 1.1978x over previous
//
#include <hip/hip_runtime.h>
#include <hip/hip_bf16.h>

// E71 Delta cell: T=2048, B=16, D=1024, N=128
// proj layout in ws: [t][b][512] f32, cols 0..127=k_hat (after norm pass),
// 128..255=v, 256..383=q, 384..511=bx

#define T_STEPS 2048
#define NB 16
#define ND 128
#define KD 1024
#define PSTRIDE 512

typedef __attribute__((ext_vector_type(4))) float f32x4;
typedef __attribute__((ext_vector_type(2))) float f32x2;
typedef __attribute__((ext_vector_type(8))) short short8v;

__device__ __forceinline__ unsigned short f2bf(float f) {
  union { float f; unsigned int u; } c; c.f = f;
  unsigned int u = c.u;
  unsigned int r = u + 0x7fffu + ((u >> 16) & 1u);   // round-to-nearest-even
  return (unsigned short)(r >> 16);
}

// ---------------------------------------------------------------------------
// Projection GEMM (unchanged, ~56us): bf16 MFMA, 128x128 tile, BK=64,
// XOR-swizzled LDS.
// ---------------------------------------------------------------------------
__global__ __launch_bounds__(256) void proj_gemm(
    const float* __restrict__ X,
    const float* __restrict__ Wk, const float* __restrict__ Wv,
    const float* __restrict__ Wq, const float* __restrict__ Wb,
    float* __restrict__ C)
{
  __shared__ unsigned short As[128 * 64];
  __shared__ unsigned short Bs[128 * 64];
  const int tid = threadIdx.x;
  const int bm = blockIdx.x;
  const int bn = blockIdx.y;
  const float* W = (bn == 0) ? Wk : ((bn == 1) ? Wv : ((bn == 2) ? Wq : Wb));
  const int lane = tid & 63;
  const int wave = tid >> 6;
  const int wr = wave >> 1, wc = wave & 1;

  f32x4 acc[4][4];
#pragma unroll
  for (int i = 0; i < 4; i++)
#pragma unroll
    for (int j = 0; j < 4; j++) acc[i][j] = (f32x4){0.f, 0.f, 0.f, 0.f};

  for (int k0 = 0; k0 < KD; k0 += 64) {
    __syncthreads();
#pragma unroll
    for (int c = 0; c < 4; c++) {
      const int g = tid + c * 256;
      const int row = g >> 3;
      const int ch = g & 7;
      const int pos = ((ch ^ (row & 7)) * 8);
      {
        const float* ga = X + (size_t)(bm * 128 + row) * KD + k0 + ch * 8;
        float4 f0 = *(const float4*)(ga);
        float4 f1 = *(const float4*)(ga + 4);
        union { unsigned short u[8]; short8v v; } pk2;
        pk2.u[0] = f2bf(f0.x); pk2.u[1] = f2bf(f0.y);
        pk2.u[2] = f2bf(f0.z); pk2.u[3] = f2bf(f0.w);
        pk2.u[4] = f2bf(f1.x); pk2.u[5] = f2bf(f1.y);
        pk2.u[6] = f2bf(f1.z); pk2.u[7] = f2bf(f1.w);
        *reinterpret_cast<short8v*>(&As[row * 64 + pos]) = pk2.v;
      }
      {
        const float* gb = W + (size_t)row * KD + k0 + ch * 8;
        float4 f0 = *(const float4*)(gb);
        float4 f1 = *(const float4*)(gb + 4);
        union { unsigned short u[8]; short8v v; } pk2;
        pk2.u[0] = f2bf(f0.x); pk2.u[1] = f2bf(f0.y);
        pk2.u[2] = f2bf(f0.z); pk2.u[3] = f2bf(f0.w);
        pk2.u[4] = f2bf(f1.x); pk2.u[5] = f2bf(f1.y);
        pk2.u[6] = f2bf(f1.z); pk2.u[7] = f2bf(f1.w);
        *reinterpret_cast<short8v*>(&Bs[row * 64 + pos]) = pk2.v;
      }
    }
    __syncthreads();
#pragma unroll
    for (int kk = 0; kk < 2; kk++) {
      const int ch = kk * 4 + (lane >> 4);
      short8v a[4], b[4];
#pragma unroll
      for (int i = 0; i < 4; i++) {
        const int ar = wr * 64 + i * 16 + (lane & 15);
        a[i] = *reinterpret_cast<const short8v*>(&As[ar * 64 + ((ch ^ (ar & 7)) * 8)]);
        const int br = wc * 64 + i * 16 + (lane & 15);
        b[i] = *reinterpret_cast<const short8v*>(&Bs[br * 64 + ((ch ^ (br & 7)) * 8)]);
      }
#pragma unroll
      for (int i = 0; i < 4; i++)
#pragma unroll
        for (int j = 0; j < 4; j++)
          acc[i][j] = __builtin_amdgcn_mfma_f32_16x16x32_bf16(a[i], b[j], acc[i][j], 0, 0, 0);
    }
  }
#pragma unroll
  for (int i = 0; i < 4; i++)
#pragma unroll
    for (int j = 0; j < 4; j++)
#pragma unroll
      for (int r = 0; r < 4; r++) {
        const int row = bm * 128 + wr * 64 + i * 16 + (lane >> 4) * 4 + r;
        const int col = bn * 128 + wc * 64 + j * 16 + (lane & 15);
        C[(size_t)row * PSTRIDE + col] = acc[i][j][r];
      }
}

// ---------------------------------------------------------------------------
// k-normalization pre-pass: proj[row][0:128] <- k / (||k|| + eps).
// ---------------------------------------------------------------------------
__global__ __launch_bounds__(256) void norm_k(float* __restrict__ proj) {
  const int lane = threadIdx.x & 63;
  const int wid = (blockIdx.x * 256 + threadIdx.x) >> 6;
  float* rowp = proj + (size_t)wid * PSTRIDE;
  float2 kv = *reinterpret_cast<float2*>(rowp + lane * 2);
  float ss = kv.x * kv.x + kv.y * kv.y;
  ss += __shfl_xor(ss, 1);
  ss += __shfl_xor(ss, 2);
  ss += __shfl_xor(ss, 4);
  ss += __shfl_xor(ss, 8);
  ss += __shfl_xor(ss, 16);
  ss += __shfl_xor(ss, 32);
  const float rn = 1.0f / (sqrtf(ss) + 1e-6f);
  kv.x *= rn; kv.y *= rn;
  *reinterpret_cast<float2*>(rowp + lane * 2) = kv;
}

// ---------------------------------------------------------------------------
// Sequential scan, R12 = R10 geometry + amdgpu_waves_per_eu(2,2).
// R10/R11 post-mortem: the backend's occupancy heuristic SPILLS to chase a
// high waves/EU target; __launch_bounds__ min-arg is only a lower bound and
// doesn't stop it (VGPR stayed 32, ring in scratch, +9GB spill traffic).
// waves_per_eu(2,2) sets max=2 -> 256-VGPR budget, no spill incentive;
// grid (2048 1-wave blocks) gives exactly 8 waves/CU = 2/EU at runtime.
// Ring flattened to named scalars (no struct/SROA path for asm outputs).
// One row per wave; per-buf 4 loads (k,q dwordx2; v,bx wave-uniform).
// Chain-decoupled r (R9 identity). Reduce = 4 DPP row_ror + shfl_xor 16/32.
// Depth-8 asm ring, counted vmcnt(24).
// ---------------------------------------------------------------------------
__device__ __forceinline__ float sum64(float v) {
  v += __int_as_float(__builtin_amdgcn_update_dpp(0, __float_as_int(v), 0x121, 0xF, 0xF, true)); // row_ror:1
  v += __int_as_float(__builtin_amdgcn_update_dpp(0, __float_as_int(v), 0x122, 0xF, 0xF, true)); // row_ror:2
  v += __int_as_float(__builtin_amdgcn_update_dpp(0, __float_as_int(v), 0x124, 0xF, 0xF, true)); // row_ror:4
  v += __int_as_float(__builtin_amdgcn_update_dpp(0, __float_as_int(v), 0x128, 0xF, 0xF, true)); // row_ror:8
  v += __shfl_xor(v, 16);
  v += __shfl_xor(v, 32);
  return v;
}

__device__ __forceinline__ float fin(float od) {
  return od * od * __builtin_amdgcn_rcpf(1.0f + __expf(-od));
}

__global__ __launch_bounds__(64)
__attribute__((amdgpu_waves_per_eu(2, 2)))
void scan_kernel(
    const float* __restrict__ proj, const float* __restrict__ S_in,
    const float* __restrict__ d_beta, const float* __restrict__ b_beta,
    float* __restrict__ out, float* __restrict__ S_out)
{
  const int lane = threadIdx.x & 63;
  const int batch = blockIdx.x & 15;   // CU's co-resident blocks share batch
  const int row = blockIdx.x >> 4;     // 0..127
  const bool w0 = (lane == 0);

  f32x2 S2 = *reinterpret_cast<const f32x2*>(
      S_in + ((size_t)batch * ND + row) * ND + lane * 2);
  const float db = d_beta[row];
  const float bb = b_beta[row];

  const float* pb = proj + (size_t)batch * PSTRIDE;
  const float* pkb = pb + lane * 2;     // k; q at +1024B
  const float* pvb = pb + 128 + row;    // v; bx at +1024B (wave-uniform)
  const size_t sstep = (size_t)NB * PSTRIDE;
  float* outp = out + (size_t)batch * ND + row;
  const size_t ostep = (size_t)NB * ND;

  // flattened depth-8 ring: named scalars only
  f32x2 kn0, kn1, kn2, kn3, kn4, kn5, kn6, kn7;
  f32x2 q0, q1, q2, q3, q4, q5, q6, q7;
  float v0, v1, v2, v3, v4, v5, v6, v7;
  float x0, x1, x2, x3, x4, x5, x6, x7;

#define LOADB(i, tt)                                                          \
  do {                                                                        \
    const float* _pk = pkb + (size_t)(tt) * sstep;                            \
    const float* _pv = pvb + (size_t)(tt) * sstep;                            \
    asm volatile("global_load_dwordx2 %0, %1, off"             : "=v"(kn##i) : "v"(_pk)); \
    asm volatile("global_load_dwordx2 %0, %1, off offset:1024" : "=v"(q##i)  : "v"(_pk)); \
    asm volatile("global_load_dword %0, %1, off"               : "=v"(v##i)  : "v"(_pv)); \
    asm volatile("global_load_dword %0, %1, off offset:1024"   : "=v"(x##i)  : "v"(_pv)); \
  } while (0)

  LOADB(0, 0); LOADB(1, 1); LOADB(2, 2); LOADB(3, 3);
  LOADB(4, 4); LOADB(5, 5); LOADB(6, 6); LOADB(7, 7);

#define WAIT24 do { asm volatile("s_waitcnt vmcnt(24)" ::: "memory"); \
                    __builtin_amdgcn_sched_barrier(0); } while (0)

  // prologue: B0,B1 ready (32 outstanding -> 24 drains exactly B0,B1)
  WAIT24;
  float pre0;
  {
    const f32x2 p = S2 * kn0;
    pre0 = sum64(p.x + p.y);            // r_0 = S0.k0, no correction
  }
  float kkp = 0.f, crp = 0.f;

#define SLOT(i, j, tnext)                                                 \
  do {                                                                    \
    WAIT24;                                                               \
    /* off-chain dots+reduces (buf i, j resident) */                      \
    const f32x2 dp = S2 * kn##j;                                          \
    const f32x2 dk = kn##i * kn##j;                                       \
    const float pre1 = sum64(dp.x + dp.y);                                \
    const float kk1  = sum64(dk.x + dk.y);                                \
    /* serial chain */                                                    \
    const float r  = fmaf(crp, kkp, pre0);                                \
    const float lg = fmaf(db, r, x##i + bb);                              \
    const float beta = __builtin_amdgcn_rcpf(1.0f + __expf(-lg));         \
    const float cr = beta * (v##i - r);                                   \
    /* S update + terminal output */                                      \
    const f32x2 cr2 = {cr, cr};                                           \
    S2 = __builtin_elementwise_fma(cr2, kn##i, S2);                       \
    const f32x2 ov = S2 * q##i;                                           \
    const float od = sum64(ov.x + ov.y);                                  \
    if (w0) *outp = fin(od);                                              \
    outp += ostep;                                                        \
    pre0 = pre1; kkp = kk1; crp = cr;                                     \
    LOADB(i, tnext);                                                      \
  } while (0)

  for (int t = 0; t < T_STEPS; t += 8) {
    const int t0 = (t +  8 < T_STEPS) ? t +  8 : T_STEPS - 1;
    const int t1 = (t +  9 < T_STEPS) ? t +  9 : T_STEPS - 1;
    const int t2 = (t + 10 < T_STEPS) ? t + 10 : T_STEPS - 1;
    const int t3 = (t + 11 < T_STEPS) ? t + 11 : T_STEPS - 1;
    const int t4 = (t + 12 < T_STEPS) ? t + 12 : T_STEPS - 1;
    const int t5 = (t + 13 < T_STEPS) ? t + 13 : T_STEPS - 1;
    const int t6 = (t + 14 < T_STEPS) ? t + 14 : T_STEPS - 1;
    const int t7 = (t + 15 < T_STEPS) ? t + 15 : T_STEPS - 1;
    SLOT(0, 1, t0);
    SLOT(1, 2, t1);
    SLOT(2, 3, t2);
    SLOT(3, 4, t3);
    SLOT(4, 5, t4);
    SLOT(5, 6, t5);
    SLOT(6, 7, t6);
    SLOT(7, 0, t7);
  }
#undef SLOT
#undef WAIT24
#undef LOADB

  asm volatile("s_waitcnt vmcnt(0)" ::: "memory");
  *reinterpret_cast<f32x2*>(
      S_out + ((size_t)batch * ND + row) * ND + lane * 2) = S2;
}

extern "C" void kernel_launch(void* const* d_in, const int* in_sizes, int n_in,
                              void* d_out, int out_size, void* d_ws, size_t ws_size,
                              hipStream_t stream) {
  const float* x  = (const float*)d_in[0];   // [2048][16][1024]
  const float* S0 = (const float*)d_in[1];   // [16][128][128]
  const float* Wk = (const float*)d_in[2];
  const float* Wv = (const float*)d_in[3];
  const float* Wq = (const float*)d_in[4];
  const float* Wb = (const float*)d_in[5];
  const float* db = (const float*)d_in[6];
  const float* bb = (const float*)d_in[7];
  float* out  = (float*)d_out;                           // [2048][16][128]
  float* Sout = out + (size_t)T_STEPS * NB * ND;         // [16][128][128]
  float* proj = (float*)d_ws;                            // [32768][512] = 64 MB

  dim3 ggrid(256, 4);
  proj_gemm<<<ggrid, 256, 0, stream>>>(x, Wk, Wv, Wq, Wb, proj);
  norm_k<<<8192, 256, 0, stream>>>(proj);
  scan_kernel<<<2048, 64, 0, stream>>>(proj, S0, db, bb, out, Sout);
}